// Round 1
// baseline (1045.975 us; speedup 1.0000x reference)
//
#include <hip/hip_runtime.h>
#include <hip/hip_bf16.h>

#define L_DIM 16384
#define C_DIM 256
#define NV 8
#define NH 4
#define DH 64
#define TL 8          // l's per block
#define NTHREADS 512  // 8 waves

typedef __attribute__((ext_vector_type(8))) short bf16x8;
typedef __attribute__((ext_vector_type(4))) float f32x4;

__device__ inline float bf2f(short s){
  union { unsigned u; float f; } v; v.u = ((unsigned)(unsigned short)s) << 16; return v.f;
}
__device__ inline short f2bf(float f){
  __hip_bfloat16 h = __float2bfloat16(f);
  union { __hip_bfloat16 h; short s; } v; v.h = h; return v.s;
}

// ---------------- prep: view_info + bf16 weight conversion ----------------
__global__ void prep_kernel(const float* __restrict__ vw, const float* __restrict__ vb,
                            const float* __restrict__ w_in, const float* __restrict__ w_out,
                            const float* __restrict__ w_g1,
                            float* __restrict__ view_info, short* __restrict__ win_hi,
                            short* __restrict__ win_lo, short* __restrict__ wout_b,
                            short* __restrict__ wg1_b){
  int tid = threadIdx.x, bid = blockIdx.x;
  if (bid == 0){
    int c = tid;                       // 256 threads, one channel each
    float rs = 0.f;
    for (int k = 0; k < C_DIM; k++) rs += vw[c*C_DIM + k];
    float b = vb[c];
    for (int n = 0; n < NV; n++) view_info[n*C_DIM + c] = (n * 0.125f) * rs + b;
  }
  int gid = bid * blockDim.x + tid;
  int stride = gridDim.x * blockDim.x;
  const int NIN = 768*256, NOUT = 256*256, NG = 64*256;
  for (int i = gid; i < NIN + NOUT + NG; i += stride){
    if (i < NIN){
      float v = w_in[i]; short hi = f2bf(v);
      win_hi[i] = hi; win_lo[i] = f2bf(v - bf2f(hi));
    } else if (i < NIN + NOUT){
      wout_b[i - NIN] = f2bf(w_out[i - NIN]);
    } else {
      wg1_b[i - NIN - NOUT] = f2bf(w_g1[i - NIN - NOUT]);
    }
  }
}

// ---------------- fused main kernel: one block = 8 l's (64 tokens) ----------------
// LDS carve (dynamic, 150080 B):
//   [0,32768)        w_hi   : staged W chunk hi, 64 rows x 256 bf16
//   [32768,65536)    w_lo   : staged W chunk lo (qkv phase only)
//   [65536,114688)   qkv    : fp32 [64][192] per-head q|k|v  -> later att bf16 [64][256]
//   [114688,147456)  ctx    : bf16 [64][256]                 -> later g1 fp32 [64][64]
//   [147456,150080)  misc   : gl[64], wgt[64], red1[256], red2[256], mu[8], rv[8]
__global__ __launch_bounds__(NTHREADS)
void fused_kernel(const float* __restrict__ feat,
                  const float* __restrict__ view_info,
                  const short* __restrict__ win_hi,
                  const short* __restrict__ win_lo,
                  const short* __restrict__ wout_b,
                  const short* __restrict__ wg1_b,
                  const float* __restrict__ b_in,
                  const float* __restrict__ b_out,
                  const float* __restrict__ b_g1,
                  const float* __restrict__ w2,
                  const float* __restrict__ b2,
                  const float* __restrict__ ln_g,
                  const float* __restrict__ ln_b,
                  float* __restrict__ out)
{
  extern __shared__ char smem[];
  short* w_hi = (short*)smem;
  short* w_lo = (short*)(smem + 32768);
  float* qkv  = (float*)(smem + 65536);
  short* att  = (short*)(smem + 65536);    // reuse after attention done
  short* ctx  = (short*)(smem + 114688);
  float* g1s  = (float*)(smem + 114688);   // reuse after out_proj done
  float* gl   = (float*)(smem + 147456);
  float* wgt  = gl + 64;
  float* red1 = wgt + 64;
  float* red2 = red1 + 256;
  float* mus  = red2 + 256;
  float* rvs  = mus + 8;

  const int tid  = threadIdx.x;
  const int wv   = tid >> 6, lane = tid & 63;
  const int rg   = wv & 3, nhv = wv >> 2;    // row-group, n-half
  const int quad = lane >> 4, l15 = lane & 15;
  const int arow = rg*16 + l15;              // A-operand token row (0..63)
  const int crow0 = rg*16 + quad*4;          // C/D row base for this lane

  // ---- stage A (features + view_info) into registers, hi/lo bf16 split ----
  bf16x8 ahi[8], alo[8];
  {
    int n = arow & 7, lloc = arow >> 3;
    long l = (long)blockIdx.x * TL + lloc;
    const float* fb = feat + ((long)n * L_DIM + l) * C_DIM;
    const float* vb = view_info + n * C_DIM;
#pragma unroll
    for (int kc = 0; kc < 8; kc++){
      int k0 = kc*32 + quad*8;
      float4 x0 = *(const float4*)(fb + k0);
      float4 x1 = *(const float4*)(fb + k0 + 4);
      float4 v0 = *(const float4*)(vb + k0);
      float4 v1 = *(const float4*)(vb + k0 + 4);
      float xs[8] = {x0.x+v0.x, x0.y+v0.y, x0.z+v0.z, x0.w+v0.w,
                     x1.x+v1.x, x1.y+v1.y, x1.z+v1.z, x1.w+v1.w};
      bf16x8 h, lo;
#pragma unroll
      for (int j = 0; j < 8; j++){
        short hb = f2bf(xs[j]);
        h[j] = hb;
        lo[j] = f2bf(xs[j] - bf2f(hb));
      }
      ahi[kc] = h; alo[kc] = lo;
    }
  }

  auto stage_w = [&](const short* __restrict__ src, short* __restrict__ dst){
    // 64 rows x 256 bf16 = 2048 x 16B slots, 512 threads -> 4 iters
#pragma unroll
    for (int i = 0; i < 4; i++){
      int slot = i*NTHREADS + tid;
      *(uint4*)(dst + slot*8) = *(const uint4*)(src + slot*8);
    }
  };

  // ================= per-head: qkv GEMM (3-term split) + attention =================
  for (int h = 0; h < NH; h++){
    for (int p = 0; p < 3; p++){            // q, k, v  (64-row W chunks, aligned)
      __syncthreads();                      // w bufs free from prior readers
      const int rowbase = p*C_DIM + h*DH;
      stage_w(win_hi + (long)rowbase*C_DIM, w_hi);
      stage_w(win_lo + (long)rowbase*C_DIM, w_lo);
      __syncthreads();
#pragma unroll
      for (int ntl = 0; ntl < 2; ntl++){
        int nt = nhv*2 + ntl;
        f32x4 acc = {0.f,0.f,0.f,0.f};
        int boff = (nt*16 + l15)*C_DIM + quad*8;
#pragma unroll
        for (int kc = 0; kc < 8; kc++){
          bf16x8 bh = *(const bf16x8*)(w_hi + boff + kc*32);
          bf16x8 bl = *(const bf16x8*)(w_lo + boff + kc*32);
          acc = __builtin_amdgcn_mfma_f32_16x16x32_bf16(ahi[kc], bh, acc, 0,0,0);
          acc = __builtin_amdgcn_mfma_f32_16x16x32_bf16(ahi[kc], bl, acc, 0,0,0);
          acc = __builtin_amdgcn_mfma_f32_16x16x32_bf16(alo[kc], bh, acc, 0,0,0);
        }
        int colc = nt*16 + l15;             // 0..63 within chunk
        float bias = b_in[rowbase + colc];
#pragma unroll
        for (int r = 0; r < 4; r++)
          qkv[(crow0 + r)*192 + p*64 + colc] = acc[r] + bias;
      }
    }
    __syncthreads();                        // qkv complete for this head
    // ---- fp32 attention for head h: wave wv handles l_loc = wv, lane = n*8+m ----
    {
      int l2 = wv;
      int nn = (tid >> 3) & 7, mm = tid & 7;
      int tq = l2*8 + nn;
      const float* qrow = qkv + tq*192;
      const float* krow = qkv + (l2*8 + mm)*192 + 64;
      float s = 0.f;
#pragma unroll
      for (int d4 = 0; d4 < 16; d4++){
        float4 q4 = *(const float4*)(qrow + d4*4);
        float4 k4 = *(const float4*)(krow + d4*4);
        s += q4.x*k4.x + q4.y*k4.y + q4.z*k4.z + q4.w*k4.w;
      }
      s *= 0.125f;                          // 1/sqrt(64)
      float mx = s;
#pragma unroll
      for (int o = 1; o < 8; o <<= 1) mx = fmaxf(mx, __shfl_xor(mx, o));
      float e = __expf(s - mx);
      float sum = e;
#pragma unroll
      for (int o = 1; o < 8; o <<= 1) sum += __shfl_xor(sum, o);
      float attnw = e / sum;
      // ctx: this thread owns d-slice [mm*8, mm*8+8) of token tq
      float c8[8] = {0,0,0,0,0,0,0,0};
#pragma unroll
      for (int mp = 0; mp < 8; mp++){
        float aw = __shfl(attnw, (nn<<3) | mp);
        const float* vrow = qkv + (l2*8 + mp)*192 + 128 + mm*8;
        float4 v0 = *(const float4*)(vrow);
        float4 v1 = *(const float4*)(vrow + 4);
        c8[0] += aw*v0.x; c8[1] += aw*v0.y; c8[2] += aw*v0.z; c8[3] += aw*v0.w;
        c8[4] += aw*v1.x; c8[5] += aw*v1.y; c8[6] += aw*v1.z; c8[7] += aw*v1.w;
      }
      bf16x8 cp;
#pragma unroll
      for (int j = 0; j < 8; j++) cp[j] = f2bf(c8[j]);
      *(bf16x8*)(ctx + tq*C_DIM + h*DH + mm*8) = cp;
    }
  }

  // ================= attended = ctx @ W_out^T + b_out (bf16 MFMA) =================
  for (int cc = 0; cc < 4; cc++){
    __syncthreads();
    stage_w(wout_b + (long)(cc*64)*C_DIM, w_hi);
    __syncthreads();
#pragma unroll
    for (int ntl = 0; ntl < 2; ntl++){
      int nt = nhv*2 + ntl;
      f32x4 acc = {0.f,0.f,0.f,0.f};
      int boff = (nt*16 + l15)*C_DIM + quad*8;
      int aoff = arow*C_DIM + quad*8;
#pragma unroll
      for (int kc = 0; kc < 8; kc++){
        bf16x8 a = *(const bf16x8*)(ctx + aoff + kc*32);
        bf16x8 b = *(const bf16x8*)(w_hi + boff + kc*32);
        acc = __builtin_amdgcn_mfma_f32_16x16x32_bf16(a, b, acc, 0,0,0);
      }
      int col = cc*64 + nt*16 + l15;
      float bias = b_out[col];
#pragma unroll
      for (int r = 0; r < 4; r++)
        att[(crow0 + r)*C_DIM + col] = f2bf(acc[r] + bias);
    }
  }

  // ================= gate hidden: g1 = relu(att @ Wg1^T + b) =================
  __syncthreads();
  stage_w(wg1_b, w_hi);
  __syncthreads();
#pragma unroll
  for (int ntl = 0; ntl < 2; ntl++){
    int nt = nhv*2 + ntl;
    f32x4 acc = {0.f,0.f,0.f,0.f};
    int boff = (nt*16 + l15)*C_DIM + quad*8;
    int aoff = arow*C_DIM + quad*8;
#pragma unroll
    for (int kc = 0; kc < 8; kc++){
      bf16x8 a = *(const bf16x8*)(att + aoff + kc*32);
      bf16x8 b = *(const bf16x8*)(w_hi + boff + kc*32);
      acc = __builtin_amdgcn_mfma_f32_16x16x32_bf16(a, b, acc, 0,0,0);
    }
    int col = nt*16 + l15;                  // 0..63
    float bias = b_g1[col];
#pragma unroll
    for (int r = 0; r < 4; r++)
      g1s[(crow0 + r)*64 + col] = fmaxf(acc[r] + bias, 0.f);
  }
  __syncthreads();

  // ---- gate scalar + sigmoid ----
  if (tid < 64){
    float s = b2[0];
    const float* g1r = g1s + tid*64;
    for (int j = 0; j < 64; j++) s += g1r[j] * w2[j];
    gl[tid] = 1.f / (1.f + __expf(-s));
  }
  __syncthreads();
  // ---- softmax over views ----
  if (tid < 8){
    float v[8]; float mx = -1e30f;
    for (int n = 0; n < 8; n++){ v[n] = gl[tid*8+n]; mx = fmaxf(mx, v[n]); }
    float sum = 0.f;
    for (int n = 0; n < 8; n++){ v[n] = __expf(v[n]-mx); sum += v[n]; }
    float inv = 1.f/sum;
    for (int n = 0; n < 8; n++) wgt[tid*8+n] = v[n]*inv;
  }
  __syncthreads();

  // ---- fused = sum_n w_n * attended, then LayerNorm over C ----
  float f8[8];
  const int lfl = tid >> 5, ccf = tid & 31;
  if (tid < 256){
    float wloc[8];
#pragma unroll
    for (int n = 0; n < 8; n++) wloc[n] = wgt[lfl*8+n];
#pragma unroll
    for (int j = 0; j < 8; j++) f8[j] = 0.f;
#pragma unroll
    for (int n = 0; n < 8; n++){
      const short* ar = att + (lfl*8+n)*C_DIM + ccf*8;
      float aw = wloc[n];
#pragma unroll
      for (int j = 0; j < 8; j++) f8[j] += aw * bf2f(ar[j]);
    }
    float s = 0.f, s2 = 0.f;
#pragma unroll
    for (int j = 0; j < 8; j++){ s += f8[j]; s2 += f8[j]*f8[j]; }
    red1[lfl*32 + ccf] = s;
    red2[lfl*32 + ccf] = s2;
  }
  __syncthreads();
  if (tid < 8){
    float s = 0.f, s2 = 0.f;
    for (int i = 0; i < 32; i++){ s += red1[tid*32+i]; s2 += red2[tid*32+i]; }
    float mu = s * (1.f/256.f);
    float var = s2 * (1.f/256.f) - mu*mu;
    mus[tid] = mu;
    rvs[tid] = rsqrtf(var + 1e-5f);
  }
  __syncthreads();
  if (tid < 256){
    float mu = mus[lfl], rv = rvs[lfl];
    long lg = (long)blockIdx.x * TL + lfl;
    float* op = out + lg * C_DIM + ccf*8;
    float o8[8];
#pragma unroll
    for (int j = 0; j < 8; j++){
      int c = ccf*8 + j;
      o8[j] = (f8[j]-mu)*rv*ln_g[c] + ln_b[c];
    }
    *(float4*)(op)   = make_float4(o8[0],o8[1],o8[2],o8[3]);
    *(float4*)(op+4) = make_float4(o8[4],o8[5],o8[6],o8[7]);
  }
}

extern "C" void kernel_launch(void* const* d_in, const int* in_sizes, int n_in,
                              void* d_out, int out_size, void* d_ws, size_t ws_size,
                              hipStream_t stream){
  const float* feat  = (const float*)d_in[0];
  const float* vw    = (const float*)d_in[1];
  const float* vb    = (const float*)d_in[2];
  const float* w_in  = (const float*)d_in[3];
  const float* b_in  = (const float*)d_in[4];
  const float* w_out = (const float*)d_in[5];
  const float* b_out = (const float*)d_in[6];
  const float* w_g1  = (const float*)d_in[7];
  const float* b_g1  = (const float*)d_in[8];
  const float* w2    = (const float*)d_in[9];
  const float* b2    = (const float*)d_in[10];
  const float* lng   = (const float*)d_in[11];
  const float* lnb   = (const float*)d_in[12];

  char* ws = (char*)d_ws;
  float* view_info = (float*)ws;              //   8192 B
  short* win_hi = (short*)(ws + 8192);        // 393216 B
  short* win_lo = (short*)(ws + 401408);      // 393216 B
  short* wout_b = (short*)(ws + 794624);      // 131072 B
  short* wg1_b  = (short*)(ws + 925696);      //  32768 B   (total 958464 B)

  prep_kernel<<<64, 256, 0, stream>>>(vw, vb, w_in, w_out, w_g1,
                                      view_info, win_hi, win_lo, wout_b, wg1_b);
  fused_kernel<<<L_DIM/TL, NTHREADS, 150080, stream>>>(
      feat, view_info, win_hi, win_lo, wout_b, wg1_b,
      b_in, b_out, b_g1, w2, b2, lng, lnb, (float*)d_out);
}

// Round 2
// 661.927 us; speedup vs baseline: 1.5802x; 1.5802x over previous
//
#include <hip/hip_runtime.h>
#include <hip/hip_bf16.h>

#define L_DIM 16384
#define C_DIM 256
#define NV 8
#define NH 4
#define DH 64
#define TL 8          // l's per block
#define NTHREADS 512  // 8 waves

// LDS row strides padded to break 128B-multiple bank aliasing:
#define WPAD 264      // bf16 rows for W tiles / ctx / att  (132 words % 32 = 4)
#define QPAD 196      // fp32 rows for qkv                  (196 % 32 = 4)
#define GPAD 65       // fp32 rows for g1s                  (65 % 32 = 1)

typedef __attribute__((ext_vector_type(8))) short bf16x8;
typedef __attribute__((ext_vector_type(4))) float f32x4;

__device__ inline float bf2f(short s){
  union { unsigned u; float f; } v; v.u = ((unsigned)(unsigned short)s) << 16; return v.f;
}
__device__ inline short f2bf(float f){
  __hip_bfloat16 h = __float2bfloat16(f);
  union { __hip_bfloat16 h; short s; } v; v.h = h; return v.s;
}

// ---------------- prep: view_info + bf16 weight conversion ----------------
__global__ void prep_kernel(const float* __restrict__ vw, const float* __restrict__ vb,
                            const float* __restrict__ w_in, const float* __restrict__ w_out,
                            const float* __restrict__ w_g1,
                            float* __restrict__ view_info, short* __restrict__ win_hi,
                            short* __restrict__ win_lo, short* __restrict__ wout_b,
                            short* __restrict__ wg1_b){
  int tid = threadIdx.x, bid = blockIdx.x;
  if (bid == 0){
    int c = tid;                       // 256 threads, one channel each
    float rs = 0.f;
    for (int k = 0; k < C_DIM; k++) rs += vw[c*C_DIM + k];
    float b = vb[c];
    for (int n = 0; n < NV; n++) view_info[n*C_DIM + c] = (n * 0.125f) * rs + b;
  }
  int gid = bid * blockDim.x + tid;
  int stride = gridDim.x * blockDim.x;
  const int NIN = 768*256, NOUT = 256*256, NG = 64*256;
  for (int i = gid; i < NIN + NOUT + NG; i += stride){
    if (i < NIN){
      float v = w_in[i]; short hi = f2bf(v);
      win_hi[i] = hi; win_lo[i] = f2bf(v - bf2f(hi));
    } else if (i < NIN + NOUT){
      wout_b[i - NIN] = f2bf(w_out[i - NIN]);
    } else {
      wg1_b[i - NIN - NOUT] = f2bf(w_g1[i - NIN - NOUT]);
    }
  }
}

// ---------------- fused main kernel: one block = 8 l's (64 tokens) ----------------
// LDS carve (dynamic, 154176 B), padded strides to kill bank conflicts:
//   [0,33792)         w_hi  : staged W chunk hi, 64 rows x WPAD bf16
//   [33792,67584)     w_lo  : staged W chunk lo (qkv phase only)
//   [67584,117760)    qkv   : fp32 [64][QPAD] per-head q|k|v
//                     att   : bf16 [64][WPAD]   (overlays qkv after attention)
//   [117760,151552)   ctx   : bf16 [64][WPAD]
//                     g1s   : fp32 [64][GPAD]   (overlays ctx after out_proj)
//   [151552,154176)   misc  : gl[64], wgt[64], red1[256], red2[256], mu[8], rv[8]
__global__ __launch_bounds__(NTHREADS)
void fused_kernel(const float* __restrict__ feat,
                  const float* __restrict__ view_info,
                  const short* __restrict__ win_hi,
                  const short* __restrict__ win_lo,
                  const short* __restrict__ wout_b,
                  const short* __restrict__ wg1_b,
                  const float* __restrict__ b_in,
                  const float* __restrict__ b_out,
                  const float* __restrict__ b_g1,
                  const float* __restrict__ w2,
                  const float* __restrict__ b2,
                  const float* __restrict__ ln_g,
                  const float* __restrict__ ln_b,
                  float* __restrict__ out)
{
  extern __shared__ char smem[];
  short* w_hi = (short*)smem;
  short* w_lo = (short*)(smem + 33792);
  float* qkv  = (float*)(smem + 67584);
  short* att  = (short*)(smem + 67584);    // overlay after attention done
  short* ctx  = (short*)(smem + 117760);
  float* g1s  = (float*)(smem + 117760);   // overlay after out_proj done
  float* gl   = (float*)(smem + 151552);
  float* wgt  = gl + 64;
  float* red1 = wgt + 64;
  float* red2 = red1 + 256;
  float* mus  = red2 + 256;
  float* rvs  = mus + 8;

  const int tid  = threadIdx.x;
  const int wv   = tid >> 6, lane = tid & 63;
  const int rg   = wv & 3, nhv = wv >> 2;    // row-group, n-half
  const int quad = lane >> 4, l15 = lane & 15;
  const int arow = rg*16 + l15;              // A-operand token row (0..63)
  const int crow0 = rg*16 + quad*4;          // C/D row base for this lane

  // ---- stage A (features + view_info) into registers, hi/lo bf16 split ----
  bf16x8 ahi[8], alo[8];
  {
    int n = arow & 7, lloc = arow >> 3;
    long l = (long)blockIdx.x * TL + lloc;
    const float* fb = feat + ((long)n * L_DIM + l) * C_DIM;
    const float* vb = view_info + n * C_DIM;
#pragma unroll
    for (int kc = 0; kc < 8; kc++){
      int k0 = kc*32 + quad*8;
      float4 x0 = *(const float4*)(fb + k0);
      float4 x1 = *(const float4*)(fb + k0 + 4);
      float4 v0 = *(const float4*)(vb + k0);
      float4 v1 = *(const float4*)(vb + k0 + 4);
      float xs[8] = {x0.x+v0.x, x0.y+v0.y, x0.z+v0.z, x0.w+v0.w,
                     x1.x+v1.x, x1.y+v1.y, x1.z+v1.z, x1.w+v1.w};
      bf16x8 h, lo;
#pragma unroll
      for (int j = 0; j < 8; j++){
        short hb = f2bf(xs[j]);
        h[j] = hb;
        lo[j] = f2bf(xs[j] - bf2f(hb));
      }
      ahi[kc] = h; alo[kc] = lo;
    }
  }

  auto stage_w = [&](const short* __restrict__ src, short* __restrict__ dst){
    // 64 rows x 256 bf16 = 2048 x 16B slots, 512 threads -> 4 iters
    // dst rows padded to WPAD shorts
#pragma unroll
    for (int i = 0; i < 4; i++){
      int slot = i*NTHREADS + tid;
      int row = slot >> 5, col = slot & 31;
      *(uint4*)(dst + row*WPAD + col*8) = *(const uint4*)(src + slot*8);
    }
  };

  // ================= per-head: qkv GEMM (3-term split) + attention =================
  for (int h = 0; h < NH; h++){
    for (int p = 0; p < 3; p++){            // q, k, v  (64-row W chunks, aligned)
      __syncthreads();                      // w bufs free from prior readers
      const int rowbase = p*C_DIM + h*DH;
      stage_w(win_hi + (long)rowbase*C_DIM, w_hi);
      stage_w(win_lo + (long)rowbase*C_DIM, w_lo);
      __syncthreads();
#pragma unroll
      for (int ntl = 0; ntl < 2; ntl++){
        int nt = nhv*2 + ntl;
        f32x4 acc = {0.f,0.f,0.f,0.f};
        int boff = (nt*16 + l15)*WPAD + quad*8;
#pragma unroll
        for (int kc = 0; kc < 8; kc++){
          bf16x8 bh = *(const bf16x8*)(w_hi + boff + kc*32);
          bf16x8 bl = *(const bf16x8*)(w_lo + boff + kc*32);
          acc = __builtin_amdgcn_mfma_f32_16x16x32_bf16(ahi[kc], bh, acc, 0,0,0);
          acc = __builtin_amdgcn_mfma_f32_16x16x32_bf16(ahi[kc], bl, acc, 0,0,0);
          acc = __builtin_amdgcn_mfma_f32_16x16x32_bf16(alo[kc], bh, acc, 0,0,0);
        }
        int colc = nt*16 + l15;             // 0..63 within chunk
        float bias = b_in[rowbase + colc];
#pragma unroll
        for (int r = 0; r < 4; r++)
          qkv[(crow0 + r)*QPAD + p*64 + colc] = acc[r] + bias;
      }
    }
    __syncthreads();                        // qkv complete for this head
    // ---- fp32 attention for head h: wave wv handles l_loc = wv, lane = n*8+m ----
    {
      int l2 = wv;
      int nn = (tid >> 3) & 7, mm = tid & 7;
      int tq = l2*8 + nn;
      const float* qrow = qkv + tq*QPAD;
      const float* krow = qkv + (l2*8 + mm)*QPAD + 64;
      float s = 0.f;
#pragma unroll
      for (int d4 = 0; d4 < 16; d4++){
        float4 q4 = *(const float4*)(qrow + d4*4);
        float4 k4 = *(const float4*)(krow + d4*4);
        s += q4.x*k4.x + q4.y*k4.y + q4.z*k4.z + q4.w*k4.w;
      }
      s *= 0.125f;                          // 1/sqrt(64)
      float mx = s;
#pragma unroll
      for (int o = 1; o < 8; o <<= 1) mx = fmaxf(mx, __shfl_xor(mx, o));
      float e = __expf(s - mx);
      float sum = e;
#pragma unroll
      for (int o = 1; o < 8; o <<= 1) sum += __shfl_xor(sum, o);
      float attnw = e / sum;
      // ctx: this thread owns d-slice [mm*8, mm*8+8) of token tq
      float c8[8] = {0,0,0,0,0,0,0,0};
#pragma unroll
      for (int mp = 0; mp < 8; mp++){
        float aw = __shfl(attnw, (nn<<3) | mp);
        const float* vrow = qkv + (l2*8 + mp)*QPAD + 128 + mm*8;
        float4 v0 = *(const float4*)(vrow);
        float4 v1 = *(const float4*)(vrow + 4);
        c8[0] += aw*v0.x; c8[1] += aw*v0.y; c8[2] += aw*v0.z; c8[3] += aw*v0.w;
        c8[4] += aw*v1.x; c8[5] += aw*v1.y; c8[6] += aw*v1.z; c8[7] += aw*v1.w;
      }
      bf16x8 cp;
#pragma unroll
      for (int j = 0; j < 8; j++) cp[j] = f2bf(c8[j]);
      *(bf16x8*)(ctx + tq*WPAD + h*DH + mm*8) = cp;
    }
  }

  // ================= attended = ctx @ W_out^T + b_out (bf16 MFMA) =================
  for (int cc = 0; cc < 4; cc++){
    __syncthreads();
    stage_w(wout_b + (long)(cc*64)*C_DIM, w_hi);
    __syncthreads();
#pragma unroll
    for (int ntl = 0; ntl < 2; ntl++){
      int nt = nhv*2 + ntl;
      f32x4 acc = {0.f,0.f,0.f,0.f};
      int boff = (nt*16 + l15)*WPAD + quad*8;
      int aoff = arow*WPAD + quad*8;
#pragma unroll
      for (int kc = 0; kc < 8; kc++){
        bf16x8 a = *(const bf16x8*)(ctx + aoff + kc*32);
        bf16x8 b = *(const bf16x8*)(w_hi + boff + kc*32);
        acc = __builtin_amdgcn_mfma_f32_16x16x32_bf16(a, b, acc, 0,0,0);
      }
      int col = cc*64 + nt*16 + l15;
      float bias = b_out[col];
#pragma unroll
      for (int r = 0; r < 4; r++)
        att[(crow0 + r)*WPAD + col] = f2bf(acc[r] + bias);
    }
  }

  // ================= gate hidden: g1 = relu(att @ Wg1^T + b) =================
  __syncthreads();
  stage_w(wg1_b, w_hi);
  __syncthreads();
#pragma unroll
  for (int ntl = 0; ntl < 2; ntl++){
    int nt = nhv*2 + ntl;
    f32x4 acc = {0.f,0.f,0.f,0.f};
    int boff = (nt*16 + l15)*WPAD + quad*8;
    int aoff = arow*WPAD + quad*8;
#pragma unroll
    for (int kc = 0; kc < 8; kc++){
      bf16x8 a = *(const bf16x8*)(att + aoff + kc*32);
      bf16x8 b = *(const bf16x8*)(w_hi + boff + kc*32);
      acc = __builtin_amdgcn_mfma_f32_16x16x32_bf16(a, b, acc, 0,0,0);
    }
    int col = nt*16 + l15;                  // 0..63
    float bias = b_g1[col];
#pragma unroll
    for (int r = 0; r < 4; r++)
      g1s[(crow0 + r)*GPAD + col] = fmaxf(acc[r] + bias, 0.f);
  }
  __syncthreads();

  // ---- gate scalar + sigmoid ----
  if (tid < 64){
    float s = b2[0];
    const float* g1r = g1s + tid*GPAD;
    for (int j = 0; j < 64; j++) s += g1r[j] * w2[j];
    gl[tid] = 1.f / (1.f + __expf(-s));
  }
  __syncthreads();
  // ---- softmax over views ----
  if (tid < 8){
    float v[8]; float mx = -1e30f;
    for (int n = 0; n < 8; n++){ v[n] = gl[tid*8+n]; mx = fmaxf(mx, v[n]); }
    float sum = 0.f;
    for (int n = 0; n < 8; n++){ v[n] = __expf(v[n]-mx); sum += v[n]; }
    float inv = 1.f/sum;
    for (int n = 0; n < 8; n++) wgt[tid*8+n] = v[n]*inv;
  }
  __syncthreads();

  // ---- fused = sum_n w_n * attended, then LayerNorm over C ----
  float f8[8];
  const int lfl = tid >> 5, ccf = tid & 31;
  if (tid < 256){
    float wloc[8];
#pragma unroll
    for (int n = 0; n < 8; n++) wloc[n] = wgt[lfl*8+n];
#pragma unroll
    for (int j = 0; j < 8; j++) f8[j] = 0.f;
#pragma unroll
    for (int n = 0; n < 8; n++){
      const short* ar = att + (lfl*8+n)*WPAD + ccf*8;
      float aw = wloc[n];
#pragma unroll
      for (int j = 0; j < 8; j++) f8[j] += aw * bf2f(ar[j]);
    }
    float s = 0.f, s2 = 0.f;
#pragma unroll
    for (int j = 0; j < 8; j++){ s += f8[j]; s2 += f8[j]*f8[j]; }
    red1[lfl*32 + ccf] = s;
    red2[lfl*32 + ccf] = s2;
  }
  __syncthreads();
  if (tid < 8){
    float s = 0.f, s2 = 0.f;
    for (int i = 0; i < 32; i++){ s += red1[tid*32+i]; s2 += red2[tid*32+i]; }
    float mu = s * (1.f/256.f);
    float var = s2 * (1.f/256.f) - mu*mu;
    mus[tid] = mu;
    rvs[tid] = rsqrtf(var + 1e-5f);
  }
  __syncthreads();
  if (tid < 256){
    float mu = mus[lfl], rv = rvs[lfl];
    long lg = (long)blockIdx.x * TL + lfl;
    float* op = out + lg * C_DIM + ccf*8;
    float o8[8];
#pragma unroll
    for (int j = 0; j < 8; j++){
      int c = ccf*8 + j;
      o8[j] = (f8[j]-mu)*rv*ln_g[c] + ln_b[c];
    }
    *(float4*)(op)   = make_float4(o8[0],o8[1],o8[2],o8[3]);
    *(float4*)(op+4) = make_float4(o8[4],o8[5],o8[6],o8[7]);
  }
}

extern "C" void kernel_launch(void* const* d_in, const int* in_sizes, int n_in,
                              void* d_out, int out_size, void* d_ws, size_t ws_size,
                              hipStream_t stream){
  const float* feat  = (const float*)d_in[0];
  const float* vw    = (const float*)d_in[1];
  const float* vb    = (const float*)d_in[2];
  const float* w_in  = (const float*)d_in[3];
  const float* b_in  = (const float*)d_in[4];
  const float* w_out = (const float*)d_in[5];
  const float* b_out = (const float*)d_in[6];
  const float* w_g1  = (const float*)d_in[7];
  const float* b_g1  = (const float*)d_in[8];
  const float* w2    = (const float*)d_in[9];
  const float* b2    = (const float*)d_in[10];
  const float* lng   = (const float*)d_in[11];
  const float* lnb   = (const float*)d_in[12];

  char* ws = (char*)d_ws;
  float* view_info = (float*)ws;              //   8192 B
  short* win_hi = (short*)(ws + 8192);        // 393216 B
  short* win_lo = (short*)(ws + 401408);      // 393216 B
  short* wout_b = (short*)(ws + 794624);      // 131072 B
  short* wg1_b  = (short*)(ws + 925696);      //  32768 B   (total 958464 B)

  prep_kernel<<<64, 256, 0, stream>>>(vw, vb, w_in, w_out, w_g1,
                                      view_info, win_hi, win_lo, wout_b, wg1_b);
  fused_kernel<<<L_DIM/TL, NTHREADS, 154176, stream>>>(
      feat, view_info, win_hi, win_lo, wout_b, wg1_b,
      b_in, b_out, b_g1, w2, b2, lng, lnb, (float*)d_out);
}